// Round 1
// 2043.594 us; speedup vs baseline: 2.3386x; 2.3386x over previous
//
#include <hip/hip_runtime.h>
#include <hip/hip_bf16.h>
#include <stdint.h>

#define DD 192
#define NSEQ 4096
#define NB 4
#define NEGV -1e9f
#define WOFF ((size_t)NB * NSEQ * DD)   // element offset of weights in d_out

// ---------------------------------------------------------------------------
// World (established rounds 0-2): ALL inputs fp32, d_out fp32,
// layout = out[4,4096,192] ++ weights[4,4096,4096].
// R3: KT (transposed K, [B][D][N]) lives in d_out[0..WOFF) — that region is
// only written by the final oproj_kernel, so it is free scratch until then.
// ---------------------------------------------------------------------------

// y[r][e] = sum_d x[r][d] * W[e][d]; fp32. block 192, 8 rows/block.
__global__ __launch_bounds__(192) void proj_kernel(
        const float* __restrict__ x, const float* __restrict__ W,
        float* __restrict__ y) {
    __shared__ float xs[8][DD];
    const int r0 = blockIdx.x * 8;
    const int t  = threadIdx.x;               // 0..191 = output column e
    for (int i = t; i < 8 * DD; i += 192)
        xs[i / DD][i % DD] = x[(size_t)r0 * DD + i];
    __syncthreads();

    float acc[8] = {0.f,0.f,0.f,0.f,0.f,0.f,0.f,0.f};
    const float* wrow = W + t * DD;
    #pragma unroll
    for (int c = 0; c < DD; c += 8) {
        float4 pa = *reinterpret_cast<const float4*>(wrow + c);
        float4 pb = *reinterpret_cast<const float4*>(wrow + c + 4);
        #pragma unroll
        for (int r = 0; r < 8; ++r) {
            const float* xr = &xs[r][c];
            acc[r] += pa.x*xr[0] + pa.y*xr[1] + pa.z*xr[2] + pa.w*xr[3]
                    + pb.x*xr[4] + pb.y*xr[5] + pb.z*xr[6] + pb.w*xr[7];
        }
    }
    #pragma unroll
    for (int r = 0; r < 8; ++r) y[(size_t)(r0 + r) * DD + t] = acc[r];
}

// kf [B][N][D] -> kt [B][D][N]. 32x32 tiles via LDS. grid (N/32, D/32, B),
// block (32,8). Both read and write fully coalesced.
__global__ __launch_bounds__(256) void transpose_kernel(
        const float* __restrict__ x, float* __restrict__ y) {
    __shared__ float tile[32][33];
    const int b  = blockIdx.z;
    const int n0 = blockIdx.x * 32, c0 = blockIdx.y * 32;
    const int tx = threadIdx.x, ty = threadIdx.y;
    const float* xb = x + (size_t)b * NSEQ * DD;
    #pragma unroll
    for (int i = ty; i < 32; i += 8)
        tile[i][tx] = xb[(size_t)(n0 + i) * DD + c0 + tx];
    __syncthreads();
    float* yb = y + (size_t)b * DD * NSEQ;
    #pragma unroll
    for (int j = ty; j < 32; j += 8)
        yb[(size_t)(c0 + j) * NSEQ + n0 + tx] = tile[tx][j];
}

// logits = q k^T + bias + mask*NEG; softmax rows; write fp32 weights to d_out.
// grid (NSEQ/8, NB), block 512 (8 waves). 8 q-rows per block.
// Thread t owns k = { 4t+u, 2048+4t+u : u=0..3 } -> acc[8 rows][8 slots].
// K is read from KT[b][c][n] (unit-stride across lanes, float4 per load).
__global__ __launch_bounds__(512, 4) void attn_softmax_kernel(
        const float* __restrict__ qws, const float* __restrict__ kt,
        const float* __restrict__ bias, const float* __restrict__ mask,
        float* __restrict__ dout) {
    const int b  = blockIdx.y;
    const int q0 = blockIdx.x * 8;
    const int t  = threadIdx.x;               // 0..511
    const int t4 = t << 2;

    __shared__ float qs[8][DD];               // 6 KB
    for (int i = t; i < 8 * DD; i += 512) {
        int r = i / DD, d = i % DD;
        qs[r][d] = qws[((size_t)(b * NSEQ + q0 + r)) * DD + d];
    }
    __syncthreads();

    float acc[8][8];
    #pragma unroll
    for (int r = 0; r < 8; ++r)
        #pragma unroll
        for (int j = 0; j < 8; ++j) acc[r][j] = 0.f;

    const float* ktb = kt + (size_t)b * DD * NSEQ;
    for (int c0 = 0; c0 < DD; c0 += 2) {
        float2 q2[8];
        #pragma unroll
        for (int r = 0; r < 8; ++r)
            q2[r] = *reinterpret_cast<const float2*>(&qs[r][c0]);   // wave-broadcast
        #pragma unroll
        for (int cc = 0; cc < 2; ++cc) {
            const float* ktc = ktb + (size_t)(c0 + cc) * NSEQ;
            const float4 k0 = *reinterpret_cast<const float4*>(ktc + t4);
            const float4 k1 = *reinterpret_cast<const float4*>(ktc + 2048 + t4);
            #pragma unroll
            for (int r = 0; r < 8; ++r) {
                const float qc = (cc == 0) ? q2[r].x : q2[r].y;
                acc[r][0] += qc * k0.x; acc[r][1] += qc * k0.y;
                acc[r][2] += qc * k0.z; acc[r][3] += qc * k0.w;
                acc[r][4] += qc * k1.x; acc[r][5] += qc * k1.y;
                acc[r][6] += qc * k1.z; acc[r][7] += qc * k1.w;
            }
        }
    }

    const int lane = t & 63, wid = t >> 6;    // 8 waves
    __shared__ float red[8][8];
    float pm[8];
    #pragma unroll
    for (int r = 0; r < 8; ++r) {
        const size_t rowoff = ((size_t)(b * NSEQ + q0 + r)) * NSEQ;
        const float4 b0 = *reinterpret_cast<const float4*>(&bias[rowoff + t4]);
        const float4 b1 = *reinterpret_cast<const float4*>(&bias[rowoff + 2048 + t4]);
        const float4 m0 = *reinterpret_cast<const float4*>(&mask[rowoff + t4]);
        const float4 m1 = *reinterpret_cast<const float4*>(&mask[rowoff + 2048 + t4]);
        acc[r][0] += b0.x + m0.x * NEGV;
        acc[r][1] += b0.y + m0.y * NEGV;
        acc[r][2] += b0.z + m0.z * NEGV;
        acc[r][3] += b0.w + m0.w * NEGV;
        acc[r][4] += b1.x + m1.x * NEGV;
        acc[r][5] += b1.y + m1.y * NEGV;
        acc[r][6] += b1.z + m1.z * NEGV;
        acc[r][7] += b1.w + m1.w * NEGV;
        float m = acc[r][0];
        #pragma unroll
        for (int j = 1; j < 8; ++j) m = fmaxf(m, acc[r][j]);
        pm[r] = m;
    }
    #pragma unroll
    for (int r = 0; r < 8; ++r) {
        float m = pm[r];
        #pragma unroll
        for (int off = 32; off; off >>= 1) m = fmaxf(m, __shfl_down(m, off));
        if (lane == 0) red[r][wid] = m;
    }
    __syncthreads();
    float rowmax[8];
    #pragma unroll
    for (int r = 0; r < 8; ++r) {
        float m = red[r][0];
        #pragma unroll
        for (int w = 1; w < 8; ++w) m = fmaxf(m, red[r][w]);
        rowmax[r] = m;
    }
    float psum[8];
    #pragma unroll
    for (int r = 0; r < 8; ++r) {
        float s = 0.f;
        #pragma unroll
        for (int j = 0; j < 8; ++j) {
            float e = __expf(acc[r][j] - rowmax[r]);
            acc[r][j] = e;
            s += e;
        }
        psum[r] = s;
    }
    __syncthreads();   // done reading red (maxes) before overwrite
    #pragma unroll
    for (int r = 0; r < 8; ++r) {
        float s = psum[r];
        #pragma unroll
        for (int off = 32; off; off >>= 1) s += __shfl_down(s, off);
        if (lane == 0) red[r][wid] = s;
    }
    __syncthreads();
    float* wout = dout + WOFF;
    #pragma unroll
    for (int r = 0; r < 8; ++r) {
        float s = red[r][0];
        #pragma unroll
        for (int w = 1; w < 8; ++w) s += red[r][w];
        const float inv = 1.0f / s;
        const size_t rowoff = ((size_t)(b * NSEQ + q0 + r)) * NSEQ;
        const float4 o0 = make_float4(acc[r][0] * inv, acc[r][1] * inv,
                                      acc[r][2] * inv, acc[r][3] * inv);
        const float4 o1 = make_float4(acc[r][4] * inv, acc[r][5] * inv,
                                      acc[r][6] * inv, acc[r][7] * inv);
        *reinterpret_cast<float4*>(&wout[rowoff + t4]) = o0;
        *reinterpret_cast<float4*>(&wout[rowoff + 2048 + t4]) = o1;
    }
}

// mid[q][e] = sum_k w[q][k] * v[k][e]; fp32 weights read back from d_out.
// grid (NSEQ/8, NB), block 64. Thread: e in {t, t+64, t+128}, 8 q-rows.
__global__ __launch_bounds__(64) void pv_kernel(
        const float* __restrict__ dout, const float* __restrict__ vws,
        float* __restrict__ mid) {
    const int b  = blockIdx.y;
    const int q0 = blockIdx.x * 8;
    const int t  = threadIdx.x;

    __shared__ float wsh[8][256];   // 8 KB
    float acc[8][3];
    #pragma unroll
    for (int r = 0; r < 8; ++r) { acc[r][0] = 0.f; acc[r][1] = 0.f; acc[r][2] = 0.f; }

    const float* wts = dout + WOFF;
    const float* vb  = vws + (size_t)b * NSEQ * DD;
    for (int k0 = 0; k0 < NSEQ; k0 += 256) {
        __syncthreads();
        for (int i = t; i < 8 * 256; i += 64) {
            const int r = i >> 8, kp = i & 255;
            wsh[r][kp] = wts[((size_t)(b * NSEQ + q0 + r)) * NSEQ + k0 + kp];
        }
        __syncthreads();
        for (int kk = 0; kk < 256; kk += 8) {
            float vv[8][3];
            #pragma unroll
            for (int i = 0; i < 8; ++i) {
                const float* vrow = &vb[(size_t)(k0 + kk + i) * DD];
                vv[i][0] = vrow[t]; vv[i][1] = vrow[t + 64]; vv[i][2] = vrow[t + 128];
            }
            #pragma unroll
            for (int r = 0; r < 8; ++r) {
                float4 pa = *reinterpret_cast<const float4*>(&wsh[r][kk]);
                float4 pb = *reinterpret_cast<const float4*>(&wsh[r][kk + 4]);
                #pragma unroll
                for (int e = 0; e < 3; ++e) {
                    acc[r][e] += pa.x * vv[0][e] + pa.y * vv[1][e] + pa.z * vv[2][e] + pa.w * vv[3][e]
                               + pb.x * vv[4][e] + pb.y * vv[5][e] + pb.z * vv[6][e] + pb.w * vv[7][e];
                }
            }
        }
    }
    #pragma unroll
    for (int r = 0; r < 8; ++r) {
        float* mrow = &mid[((size_t)(b * NSEQ + q0 + r)) * DD];
        mrow[t] = acc[r][0]; mrow[t + 64] = acc[r][1]; mrow[t + 128] = acc[r][2];
    }
}

// final[r][o] = sum_e mid[r][e] * OW[o][e]; fp32 out to d_out[0..].
__global__ __launch_bounds__(192) void oproj_kernel(
        const float* __restrict__ x, const float* __restrict__ W,
        float* __restrict__ y) {
    __shared__ float xs[8][DD];
    const int r0 = blockIdx.x * 8;
    const int t  = threadIdx.x;
    for (int i = t; i < 8 * DD; i += 192)
        xs[i / DD][i % DD] = x[(size_t)r0 * DD + i];
    __syncthreads();

    float acc[8] = {0.f,0.f,0.f,0.f,0.f,0.f,0.f,0.f};
    const float* wrow = W + t * DD;
    #pragma unroll
    for (int c = 0; c < DD; c += 8) {
        float4 pa = *reinterpret_cast<const float4*>(wrow + c);
        float4 pb = *reinterpret_cast<const float4*>(wrow + c + 4);
        #pragma unroll
        for (int r = 0; r < 8; ++r) {
            const float* xr = &xs[r][c];
            acc[r] += pa.x*xr[0] + pa.y*xr[1] + pa.z*xr[2] + pa.w*xr[3]
                    + pb.x*xr[4] + pb.y*xr[5] + pb.z*xr[6] + pb.w*xr[7];
        }
    }
    #pragma unroll
    for (int r = 0; r < 8; ++r) y[(size_t)(r0 + r) * DD + t] = acc[r];
}

extern "C" void kernel_launch(void* const* d_in, const int* in_sizes, int n_in,
                              void* d_out, int out_size, void* d_ws, size_t ws_size,
                              hipStream_t stream) {
    const float* query = (const float*)d_in[0];
    const float* key   = (const float*)d_in[1];
    const float* value = (const float*)d_in[2];
    const float* mask  = (const float*)d_in[3];
    const float* bias  = (const float*)d_in[4];
    const float* qw    = (const float*)d_in[5];
    const float* kw    = (const float*)d_in[6];
    const float* vw    = (const float*)d_in[7];
    const float* ow    = (const float*)d_in[8];

    const size_t nrows = (size_t)NB * NSEQ;   // 16384
    float* dout = (float*)d_out;

    // workspace: q | k | v fp32 (37.75 MB). mid aliases q (dead after softmax).
    float* qf  = (float*)d_ws;
    float* kf  = qf + nrows * DD;
    float* vf  = kf + nrows * DD;
    float* mid = qf;

    // KT[b][c][n] scratch lives in d_out[0..WOFF): only oproj (last kernel)
    // writes that region, and attn only touches d_out[WOFF..] for weights.
    float* ktp = dout;

    proj_kernel<<<dim3(nrows / 8), 192, 0, stream>>>(query, qw, qf);
    proj_kernel<<<dim3(nrows / 8), 192, 0, stream>>>(key,   kw, kf);
    proj_kernel<<<dim3(nrows / 8), 192, 0, stream>>>(value, vw, vf);

    transpose_kernel<<<dim3(NSEQ / 32, DD / 32, NB), dim3(32, 8), 0, stream>>>(kf, ktp);

    attn_softmax_kernel<<<dim3(NSEQ / 8, NB), 512, 0, stream>>>(
        qf, ktp, bias, mask, dout);

    pv_kernel<<<dim3(NSEQ / 8, NB), 64, 0, stream>>>(dout, vf, mid);

    oproj_kernel<<<dim3(nrows / 8), 192, 0, stream>>>(mid, ow, dout);
}